// Round 1
// 621.064 us; speedup vs baseline: 1.0262x; 1.0262x over previous
//
#include <hip/hip_runtime.h>
#include <cstdint>
#include <cstddef>

#define D_MODEL 1024
#define SEQ     4096
#define BATCH   4
#define M_ROWS  (BATCH*SEQ)   // 16384
#define NCHUNK  64
#define LCHUNK  (SEQ/NCHUNK)  // 64

typedef __bf16 bf16_t;
typedef __bf16 bf16x8 __attribute__((ext_vector_type(8)));
typedef __bf16 bf16x4 __attribute__((ext_vector_type(4)));
typedef float  f32x4  __attribute__((ext_vector_type(4)));

// ---------------------------------------------------------------- utilities
__device__ __forceinline__ void load_lds_128(const bf16_t* g, bf16_t* l) {
    __builtin_amdgcn_global_load_lds(
        (const __attribute__((address_space(1))) unsigned int*)g,
        (__attribute__((address_space(3))) unsigned int*)l,
        16, 0, 0);
}

__device__ __forceinline__ float2 bf16pair_to_f2(unsigned int u) {
    union { unsigned int i; float f; } a, b;
    a.i = u << 16;          // low element
    b.i = u & 0xffff0000u;  // high element
    float2 r; r.x = a.f; r.y = b.f; return r;
}

// ---------------------------------------------- fused weight convert+transpose
// all four weights in one launch; in: f32 (R,C) row-major -> out: bf16 (C,R)
__global__ __launch_bounds__(256)
void transpose_all(const float* __restrict__ gate_w, const float* __restrict__ value_w,
                   const float* __restrict__ ffn_w1, const float* __restrict__ ffn_w2,
                   bf16_t* __restrict__ wgv_t, bf16_t* __restrict__ w1_t,
                   bf16_t* __restrict__ w2_t) {
    int id = blockIdx.x;
    const float* in; bf16_t* outp; int R, C, bx, by;
    if (id < 1024)      { in = gate_w;  outp = wgv_t;               R = 1024; C = 1024; bx = id & 31;  by = id >> 5; }
    else if (id < 2048) { id -= 1024; in = value_w; outp = wgv_t + 1024*1024; R = 1024; C = 1024; bx = id & 31;  by = id >> 5; }
    else if (id < 6144) { id -= 2048; in = ffn_w1;  outp = w1_t;    R = 1024; C = 4096; bx = id & 127; by = id >> 7; }
    else                { id -= 6144; in = ffn_w2;  outp = w2_t;    R = 4096; C = 1024; bx = id & 31;  by = id >> 5; }
    __shared__ float t[32][33];
    int tx = threadIdx.x & 31, ty = threadIdx.x >> 5;   // 32 x 8
    int c0 = bx * 32, r0 = by * 32;
    #pragma unroll
    for (int j = 0; j < 32; j += 8)
        t[ty + j][tx] = in[(size_t)(r0 + ty + j) * C + c0 + tx];
    __syncthreads();
    #pragma unroll
    for (int j = 0; j < 32; j += 8)
        outp[(size_t)(c0 + ty + j) * R + r0 + tx] = (bf16_t)t[tx][ty + j];
}

// ---------------------------------------------------------------- layernorm
__global__ __launch_bounds__(256)
void ln_kernel(const float* __restrict__ x, const float* __restrict__ gamma,
               const float* __restrict__ beta, bf16_t* __restrict__ h) {
    int row = blockIdx.x;
    int tid = threadIdx.x;
    const float4* xr = (const float4*)(x + (size_t)row * D_MODEL);
    float4 v = xr[tid];
    float s  = v.x + v.y + v.z + v.w;
    float ss = v.x*v.x + v.y*v.y + v.z*v.z + v.w*v.w;
    #pragma unroll
    for (int off = 32; off; off >>= 1) {
        s  += __shfl_down(s, off);
        ss += __shfl_down(ss, off);
    }
    __shared__ float red[8];
    int wave = tid >> 6, lane = tid & 63;
    if (lane == 0) { red[wave] = s; red[4 + wave] = ss; }
    __syncthreads();
    if (tid == 0) {
        float S  = red[0] + red[1] + red[2] + red[3];
        float SS = red[4] + red[5] + red[6] + red[7];
        float mean = S * (1.0f / D_MODEL);
        float var  = SS * (1.0f / D_MODEL) - mean * mean;
        red[0] = mean;
        red[1] = rsqrtf(var + 1e-5f);
    }
    __syncthreads();
    float mean = red[0], rstd = red[1];
    float4 gv = ((const float4*)gamma)[tid];
    float4 bv = ((const float4*)beta)[tid];
    bf16x4 o;
    o[0] = (bf16_t)((v.x - mean) * rstd * gv.x + bv.x);
    o[1] = (bf16_t)((v.y - mean) * rstd * gv.y + bv.y);
    o[2] = (bf16_t)((v.z - mean) * rstd * gv.z + bv.z);
    o[3] = (bf16_t)((v.w - mean) * rstd * gv.w + bv.w);
    ((bf16x4*)h)[(size_t)row * (D_MODEL / 4) + tid] = o;
}

// ---------------------------------------------------------------- GEMM 256x256, 8-phase
// A: bf16 (M,K) row-major.  Bt: bf16 (N,K) row-major.
// 8-phase counted-vmcnt schedule (T3+T4+T5 on top of the verified XOR chunk
// swizzle). 512 thr = 8 waves (2M x 4N), per-wave 128x64 output, BK=64,
// 2 K-tiles per iteration. Even K-tiles live in buf0, odd in buf1 (static).
//
// Per iteration i (tiles T=2i in buf0, T+1 in buf1):
//   P1: rd A.m0-3+B.n0-1(buf0) | stage A.h0(T+1)->buf1 | mfma m0-3 x n0-1
//   P2: rd B.n2-3(buf0)        | stage A.h1(T+1)->buf1 | mfma m0-3 x n2-3
//   P3: rd A.m4-7(buf0)        | stage B.h0(T+2)->buf0 | mfma m4-7 x n0-1
//   P4:                        | stage B.h1(T+2)->buf0 | mfma m4-7 x n2-3 | vmcnt(4)
//   P5-P8: mirror on buf1, staging A(T+2)->buf0, B(T+3)->buf1 | vmcnt(4) @P8
// Ledger: each wave issues exactly 2 global_load_lds per phase. vmcnt(4) at
// P4/P8 leaves the last 2 phases' loads in flight while guaranteeing the
// next tile's 4 half-tiles have landed. Every staged region's last ds_read
// finished >=1 barrier earlier (raw s_barrier; lgkmcnt(0) drains reads
// before each MFMA cluster, so phase-end barrier implies reads complete).
// Tail: prefetch tile index clamped to KT-1 (junk loads keep ledger exact,
// land in dead regions); vmcnt(0) before epilogue so no LDS-DMA outlives WG.
// MODE 2: out_bf16 = gelu_exact(acc + bias)
// MODE 3: out_f32  = xres + acc + bias
// MODE 4: fused gate/value: n<1024 -> sigmoid(acc+bias) -> out; else acc+bias2 -> out2
#define PHASE_MID() do { __builtin_amdgcn_s_barrier(); \
    asm volatile("s_waitcnt lgkmcnt(0)" ::: "memory"); \
    __builtin_amdgcn_s_setprio(1); } while (0)
#define PHASE_END() do { __builtin_amdgcn_s_setprio(0); \
    __builtin_amdgcn_s_barrier(); } while (0)
#define PHASE_END_VM() do { __builtin_amdgcn_s_setprio(0); \
    asm volatile("s_waitcnt vmcnt(4)" ::: "memory"); \
    __builtin_amdgcn_s_barrier(); } while (0)

#define LDA4(BUF, MB) do { _Pragma("unroll") for (int m_ = 0; m_ < 4; ++m_) { \
    af[m_][0] = *(const bf16x8*)((BUF) + aoff0 + ((MB)*4 + m_) * 1024); \
    af[m_][1] = *(const bf16x8*)((BUF) + aoff1 + ((MB)*4 + m_) * 1024); } } while (0)
#define LDB2(BUF, NLO) do { _Pragma("unroll") for (int n_ = 0; n_ < 2; ++n_) { \
    bfr[(NLO)+n_][0] = *(const bf16x8*)((BUF) + boff0 + ((NLO)+n_) * 1024); \
    bfr[(NLO)+n_][1] = *(const bf16x8*)((BUF) + boff1 + ((NLO)+n_) * 1024); } } while (0)
#define MFMA_HALF(MB, NLO) do { _Pragma("unroll") for (int m_ = 0; m_ < 4; ++m_) { \
    _Pragma("unroll") for (int n_ = 0; n_ < 2; ++n_) { \
        acc[(MB)*4 + m_][(NLO) + n_] = __builtin_amdgcn_mfma_f32_16x16x32_bf16( \
            bfr[(NLO)+n_][0], af[m_][0], acc[(MB)*4 + m_][(NLO) + n_], 0, 0, 0); \
        acc[(MB)*4 + m_][(NLO) + n_] = __builtin_amdgcn_mfma_f32_16x16x32_bf16( \
            bfr[(NLO)+n_][1], af[m_][1], acc[(MB)*4 + m_][(NLO) + n_], 0, 0, 0); } } } while (0)

template <int MODE, int TN>
__global__ __launch_bounds__(512, 2)
void gemm256(const bf16_t* __restrict__ A, const bf16_t* __restrict__ Bt,
             const float* __restrict__ bias, const float* __restrict__ bias2,
             const float* __restrict__ xres,
             void* __restrict__ out, void* __restrict__ out2,
             int M, int N, int K) {
    __shared__ __align__(16) bf16_t lds[2][2][256 * 64];   // [buf][A=0/B=1], 128 KiB

    const int tid  = threadIdx.x;
    const int lane = tid & 63;
    const int wave = tid >> 6;
    const int wm   = wave >> 2;      // 0..1  (m half)
    const int wn   = wave & 3;       // 0..3  (n quarter)

    const int L  = blockIdx.x;
    const int r  = L >> 3;
    const int n0 = (r % TN) * 256;
    const int m0 = ((L & 7) + 8 * (r / TN)) * 256;   // XCD-partitioned m-band

    f32x4 acc[8][4];
    #pragma unroll
    for (int i = 0; i < 8; i++)
        #pragma unroll
        for (int j = 0; j < 4; j++) acc[i][j] = (f32x4){0.f, 0.f, 0.f, 0.f};

    // staging invariants: chunk c = round*512 + tid; row = c>>3 (0..127),
    // source col8 pre-swizzled by row&7 so linear LDS holds the XOR layout.
    const int rr = tid >> 3;                        // 0..63
    const int sc = ((tid & 7) ^ (rr & 7)) * 8;      // swizzled col (bf16 units)
    const bf16_t* pa = A  + ((size_t)(m0 + rr)) * K + sc;
    const bf16_t* pb = Bt + ((size_t)(n0 + rr)) * K + sc;
    const size_t rstep = (size_t)64 * K;            // rows 64..127 of a half
    const size_t hstep = rstep * 2;                 // half-tile stride (128 rows)

    // frag-read invariants
    const int l16 = lane & 15, quad = lane >> 4, swz = l16 & 7;
    const int aoff0 = (wm*128 + l16)*64 + ((quad    ) ^ swz)*8;
    const int aoff1 = (wm*128 + l16)*64 + ((quad + 4) ^ swz)*8;
    const int boff0 = (wn*64  + l16)*64 + ((quad    ) ^ swz)*8;
    const int boff1 = (wn*64  + l16)*64 + ((quad + 4) ^ swz)*8;

    bf16_t* LA0 = &lds[0][0][0]; bf16_t* LB0 = &lds[0][1][0];
    bf16_t* LA1 = &lds[1][0][0]; bf16_t* LB1 = &lds[1][1][0];

    const int KT = K >> 6;        // 64-wide K-tiles (16 or 64 here; always even)
    const int NI = KT >> 1;

    auto STAGE = [&](const bf16_t* gsrc, bf16_t* dst) {
        load_lds_128(gsrc,         dst + tid * 8);
        load_lds_128(gsrc + rstep, dst + 4096 + tid * 8);
    };

    // prologue: B(0), A(0), B(1)  (6 half-tiles = 12 loads/wave)
    STAGE(pb,              LB0);
    STAGE(pb + hstep,      LB0 + 8192);
    STAGE(pa,              LA0);
    STAGE(pa + hstep,      LA0 + 8192);
    STAGE(pb + 64,         LB1);
    STAGE(pb + hstep + 64, LB1 + 8192);
    asm volatile("s_waitcnt vmcnt(4)" ::: "memory");   // tile 0 landed
    __builtin_amdgcn_s_barrier();

    for (int it = 0; it < NI; ++it) {
        const int k1 = (2*it + 1) * 64;
        const int t2 = (2*it + 2 < KT) ? 2*it + 2 : KT - 1;   // clamp = tail junk
        const int t3 = (2*it + 3 < KT) ? 2*it + 3 : KT - 1;
        const int k2 = t2 * 64, k3 = t3 * 64;

        bf16x8 af[4][2], bfr[4][2];

        // P1
        LDA4(LA0, 0); LDB2(LB0, 0);
        STAGE(pa + k1, LA1);
        PHASE_MID(); MFMA_HALF(0, 0); PHASE_END();
        // P2
        LDB2(LB0, 2);
        STAGE(pa + hstep + k1, LA1 + 8192);
        PHASE_MID(); MFMA_HALF(0, 2); PHASE_END();
        // P3
        LDA4(LA0, 1);
        STAGE(pb + k2, LB0);
        PHASE_MID(); MFMA_HALF(1, 0); PHASE_END();
        // P4
        STAGE(pb + hstep + k2, LB0 + 8192);
        PHASE_MID(); MFMA_HALF(1, 2); PHASE_END_VM();   // tile 2it+1 landed
        // P5
        LDA4(LA1, 0); LDB2(LB1, 0);
        STAGE(pa + k2, LA0);
        PHASE_MID(); MFMA_HALF(0, 0); PHASE_END();
        // P6
        LDB2(LB1, 2);
        STAGE(pa + hstep + k2, LA0 + 8192);
        PHASE_MID(); MFMA_HALF(0, 2); PHASE_END();
        // P7
        LDA4(LA1, 1);
        STAGE(pb + k3, LB1);
        PHASE_MID(); MFMA_HALF(1, 0); PHASE_END();
        // P8
        STAGE(pb + hstep + k3, LB1 + 8192);
        PHASE_MID(); MFMA_HALF(1, 2); PHASE_END_VM();   // tile 2it+2 landed
    }

    // drain tail junk LDS-DMA before the workgroup can retire
    asm volatile("s_waitcnt vmcnt(0)" ::: "memory");

    // epilogue: lane holds C[m0+wm*128+mt*16+l16][n0+wn*64+nt*16+quad*4 + j]
    #pragma unroll
    for (int mt = 0; mt < 8; ++mt) {
        int row = m0 + wm * 128 + mt * 16 + l16;
        #pragma unroll
        for (int nt = 0; nt < 4; ++nt) {
            int col = n0 + wn * 64 + nt * 16 + quad * 4;
            f32x4 a = acc[mt][nt];
            if (MODE == 4) {
                bool isV = (n0 >= 1024);         // block-uniform
                int c1 = col & 1023;
                float4 bv = *(const float4*)((isV ? bias2 : bias) + c1);
                float4 val;
                val.x = a[0] + bv.x; val.y = a[1] + bv.y;
                val.z = a[2] + bv.z; val.w = a[3] + bv.w;
                if (!isV) {
                    val.x = 1.0f / (1.0f + __expf(-val.x));
                    val.y = 1.0f / (1.0f + __expf(-val.y));
                    val.z = 1.0f / (1.0f + __expf(-val.z));
                    val.w = 1.0f / (1.0f + __expf(-val.w));
                }
                bf16x4 p;
                p[0] = (bf16_t)val.x; p[1] = (bf16_t)val.y;
                p[2] = (bf16_t)val.z; p[3] = (bf16_t)val.w;
                bf16_t* o = (bf16_t*)(isV ? out2 : out);
                *(bf16x4*)(o + (size_t)row * 1024 + c1) = p;
            } else if (MODE == 2) {
                float4 bv = *(const float4*)(bias + col);
                float4 val;
                val.x = a[0] + bv.x; val.y = a[1] + bv.y;
                val.z = a[2] + bv.z; val.w = a[3] + bv.w;
                val.x = 0.5f * val.x * (1.0f + erff(val.x * 0.70710678118654752f));
                val.y = 0.5f * val.y * (1.0f + erff(val.y * 0.70710678118654752f));
                val.z = 0.5f * val.z * (1.0f + erff(val.z * 0.70710678118654752f));
                val.w = 0.5f * val.w * (1.0f + erff(val.w * 0.70710678118654752f));
                bf16x4 p;
                p[0] = (bf16_t)val.x; p[1] = (bf16_t)val.y;
                p[2] = (bf16_t)val.z; p[3] = (bf16_t)val.w;
                *(bf16x4*)((bf16_t*)out + (size_t)row * N + col) = p;
            } else { // MODE 3
                float4 bv = *(const float4*)(bias + col);
                float4 xr = *(const float4*)(xres + (size_t)row * N + col);
                float4 val;
                val.x = xr.x + a[0] + bv.x; val.y = xr.y + a[1] + bv.y;
                val.z = xr.z + a[2] + bv.z; val.w = xr.w + a[3] + bv.w;
                *(float4*)((float*)out + (size_t)row * N + col) = val;
            }
        }
    }
}

// ---------------------------------------------------------------- scan
// phase A: per-chunk sums of g and g*v
__global__ __launch_bounds__(256)
void scan_partial(const bf16_t* __restrict__ g, const bf16_t* __restrict__ v,
                  float* __restrict__ sg, float* __restrict__ sgv) {
    int dt = blockIdx.x & 1;
    int c  = (blockIdx.x >> 1) & (NCHUNK - 1);
    int b  = blockIdx.x >> 7;
    int d  = dt * 512 + threadIdx.x * 2;
    float s0 = 0.f, s1 = 0.f, t0 = 0.f, t1 = 0.f;
    for (int i = 0; i < LCHUNK; i++) {
        int s = c * LCHUNK + i;
        size_t idx = ((size_t)(b * SEQ + s)) * D_MODEL + d;
        float2 gf = bf16pair_to_f2(*(const unsigned int*)(g + idx));
        float2 vf = bf16pair_to_f2(*(const unsigned int*)(v + idx));
        s0 += gf.x; s1 += gf.y;
        t0 += gf.x * vf.x; t1 += gf.y * vf.y;
    }
    size_t o = ((size_t)(b * NCHUNK + c)) * D_MODEL + d;
    sg[o] = s0;  sg[o + 1] = s1;
    sgv[o] = t0; sgv[o + 1] = t1;
}

// phase B+C fused: each block sums partials of chunks < c (2 MB, L2-resident),
// then applies x_new = x + cumsum(g*v)/(cumsum(g)+eps)
__global__ __launch_bounds__(256)
void scan_apply(const bf16_t* __restrict__ g, const bf16_t* __restrict__ v,
                const float* __restrict__ x, const float* __restrict__ sg,
                const float* __restrict__ sgv, float* __restrict__ out) {
    int dt = blockIdx.x & 1;
    int c  = (blockIdx.x >> 1) & (NCHUNK - 1);
    int b  = blockIdx.x >> 7;
    int d  = dt * 512 + threadIdx.x * 2;
    float rg0 = 0.f, rg1 = 0.f, rv0 = 0.f, rv1 = 0.f;
    for (int p = 0; p < c; p++) {
        size_t o = ((size_t)(b * NCHUNK + p)) * D_MODEL + d;
        float2 a  = *(const float2*)(sg + o);
        float2 bb = *(const float2*)(sgv + o);
        rg0 += a.x;  rg1 += a.y;
        rv0 += bb.x; rv1 += bb.y;
    }
    for (int i = 0; i < LCHUNK; i++) {
        int s = c * LCHUNK + i;
        size_t idx = ((size_t)(b * SEQ + s)) * D_MODEL + d;
        float2 gf = bf16pair_to_f2(*(const unsigned int*)(g + idx));
        float2 vf = bf16pair_to_f2(*(const unsigned int*)(v + idx));
        rv0 += gf.x * vf.x; rg0 += gf.x;
        rv1 += gf.y * vf.y; rg1 += gf.y;
        float2 xv = *(const float2*)(x + idx);
        float2 ov;
        ov.x = xv.x + rv0 / (rg0 + 1e-6f);
        ov.y = xv.y + rv1 / (rg1 + 1e-6f);
        *(float2*)(out + idx) = ov;
    }
}

// ---------------------------------------------------------------- launcher
extern "C" void kernel_launch(void* const* d_in, const int* in_sizes, int n_in,
                              void* d_out, int out_size, void* d_ws, size_t ws_size,
                              hipStream_t stream) {
    (void)in_sizes; (void)n_in; (void)out_size; (void)ws_size;
    const float* x       = (const float*)d_in[0];
    const float* ln1_g   = (const float*)d_in[1];
    const float* ln1_b   = (const float*)d_in[2];
    const float* ln2_g   = (const float*)d_in[3];
    const float* ln2_b   = (const float*)d_in[4];
    const float* gate_w  = (const float*)d_in[5];
    const float* gate_b  = (const float*)d_in[6];
    const float* value_w = (const float*)d_in[7];
    const float* value_b = (const float*)d_in[8];
    const float* ffn_w1  = (const float*)d_in[9];
    const float* ffn_b1  = (const float*)d_in[10];
    const float* ffn_w2  = (const float*)d_in[11];
    const float* ffn_b2  = (const float*)d_in[12];
    float* out = (float*)d_out;

    char* ws = (char*)d_ws;
    const size_t MB = 1024 * 1024;
    bf16_t* wgv_t = (bf16_t*)(ws + 0 * MB);     // (2048,1024) bf16   4 MB
    bf16_t* w1_t  = (bf16_t*)(ws + 4 * MB);     // (4096,1024) bf16   8 MB
    bf16_t* w2_t  = (bf16_t*)(ws + 12 * MB);    // (1024,4096) bf16   8 MB
    bf16_t* h     = (bf16_t*)(ws + 20 * MB);    // (16384,1024) bf16 32 MB (reused as h2)
    bf16_t* g     = (bf16_t*)(ws + 52 * MB);    // (16384,1024) bf16 32 MB
    bf16_t* v     = (bf16_t*)(ws + 84 * MB);    // (16384,1024) bf16 32 MB
    float*  sg    = (float*)(ws + 116 * MB);    // (4,64,1024) f32    1 MB
    float*  sgv   = (float*)(ws + 117 * MB);    // (4,64,1024) f32    1 MB
    bf16_t* act   = (bf16_t*)(ws + 118 * MB);   // (16384,4096) bf16 128 MB

    // 1. all weight transposes in one launch
    transpose_all<<<10240, 256, 0, stream>>>(gate_w, value_w, ffn_w1, ffn_w2,
                                             wgv_t, w1_t, w2_t);

    // 2. h = LN1(x)
    ln_kernel<<<M_ROWS, 256, 0, stream>>>(x, ln1_g, ln1_b, h);

    // 3. fused: g = sigmoid(h@gate_w + gate_b); v = h@value_w + value_b
    gemm256<4, 8><<<8 * 64, 512, 0, stream>>>(
        h, wgv_t, gate_b, value_b, nullptr, g, v, M_ROWS, 2048, 1024);

    // 4. x_new = x + cumsum(g*v)/(cumsum(g)+eps)  -> d_out
    scan_partial<<<BATCH * NCHUNK * 2, 256, 0, stream>>>(g, v, sg, sgv);
    scan_apply<<<BATCH * NCHUNK * 2, 256, 0, stream>>>(g, v, x, sg, sgv, out);

    // 5. h2 = LN2(x_new)
    ln_kernel<<<M_ROWS, 256, 0, stream>>>(out, ln2_g, ln2_b, h);

    // 6. act = gelu(h2@ffn_w1 + ffn_b1)
    gemm256<2, 16><<<16 * 64, 512, 0, stream>>>(
        h, w1_t, ffn_b1, nullptr, nullptr, act, nullptr, M_ROWS, 4096, 1024);

    // 7. out = x_new + act@ffn_w2 + ffn_b2
    gemm256<3, 4><<<4 * 64, 512, 0, stream>>>(
        act, w2_t, ffn_b2, nullptr, out, out, nullptr, M_ROWS, 1024, 4096);
}

// Round 2
// 596.515 us; speedup vs baseline: 1.0684x; 1.0412x over previous
//
#include <hip/hip_runtime.h>
#include <cstdint>
#include <cstddef>

#define D_MODEL 1024
#define SEQ     4096
#define BATCH   4
#define M_ROWS  (BATCH*SEQ)   // 16384
#define NCHUNK  64
#define LCHUNK  (SEQ/NCHUNK)  // 64

typedef __bf16 bf16_t;
typedef __bf16 bf16x8 __attribute__((ext_vector_type(8)));
typedef __bf16 bf16x4 __attribute__((ext_vector_type(4)));
typedef float  f32x4  __attribute__((ext_vector_type(4)));

// ---------------------------------------------------------------- utilities
__device__ __forceinline__ void load_lds_128(const bf16_t* g, bf16_t* l) {
    __builtin_amdgcn_global_load_lds(
        (const __attribute__((address_space(1))) unsigned int*)g,
        (__attribute__((address_space(3))) unsigned int*)l,
        16, 0, 0);
}

__device__ __forceinline__ float2 bf16pair_to_f2(unsigned int u) {
    union { unsigned int i; float f; } a, b;
    a.i = u << 16;          // low element
    b.i = u & 0xffff0000u;  // high element
    float2 r; r.x = a.f; r.y = b.f; return r;
}

// tanh-form GELU: max |err| vs exact erf-GELU ~5e-4, below bf16 quantization
// of the activation tensor; one v_exp instead of erff's ~20-op polynomial.
__device__ __forceinline__ float gelu_f(float x) {
    float t = x * x;
    float u = x * (1.5957691216f + 0.07135481627f * t);   // 2c(x+0.044715x^3)
    return x / (1.0f + __expf(-u));
}

// ---------------------------------------------- fused weight convert+transpose
// all four weights in one launch; in: f32 (R,C) row-major -> out: bf16 (C,R)
__global__ __launch_bounds__(256)
void transpose_all(const float* __restrict__ gate_w, const float* __restrict__ value_w,
                   const float* __restrict__ ffn_w1, const float* __restrict__ ffn_w2,
                   bf16_t* __restrict__ wgv_t, bf16_t* __restrict__ w1_t,
                   bf16_t* __restrict__ w2_t) {
    int id = blockIdx.x;
    const float* in; bf16_t* outp; int R, C, bx, by;
    if (id < 1024)      { in = gate_w;  outp = wgv_t;               R = 1024; C = 1024; bx = id & 31;  by = id >> 5; }
    else if (id < 2048) { id -= 1024; in = value_w; outp = wgv_t + 1024*1024; R = 1024; C = 1024; bx = id & 31;  by = id >> 5; }
    else if (id < 6144) { id -= 2048; in = ffn_w1;  outp = w1_t;    R = 1024; C = 4096; bx = id & 127; by = id >> 7; }
    else                { id -= 6144; in = ffn_w2;  outp = w2_t;    R = 4096; C = 1024; bx = id & 31;  by = id >> 5; }
    __shared__ float t[32][33];
    int tx = threadIdx.x & 31, ty = threadIdx.x >> 5;   // 32 x 8
    int c0 = bx * 32, r0 = by * 32;
    #pragma unroll
    for (int j = 0; j < 32; j += 8)
        t[ty + j][tx] = in[(size_t)(r0 + ty + j) * C + c0 + tx];
    __syncthreads();
    #pragma unroll
    for (int j = 0; j < 32; j += 8)
        outp[(size_t)(c0 + ty + j) * R + r0 + tx] = (bf16_t)t[tx][ty + j];
}

// ---------------------------------------------------------------- layernorm
__global__ __launch_bounds__(256)
void ln_kernel(const float* __restrict__ x, const float* __restrict__ gamma,
               const float* __restrict__ beta, bf16_t* __restrict__ h) {
    int row = blockIdx.x;
    int tid = threadIdx.x;
    const float4* xr = (const float4*)(x + (size_t)row * D_MODEL);
    float4 v = xr[tid];
    float s  = v.x + v.y + v.z + v.w;
    float ss = v.x*v.x + v.y*v.y + v.z*v.z + v.w*v.w;
    #pragma unroll
    for (int off = 32; off; off >>= 1) {
        s  += __shfl_down(s, off);
        ss += __shfl_down(ss, off);
    }
    __shared__ float red[8];
    int wave = tid >> 6, lane = tid & 63;
    if (lane == 0) { red[wave] = s; red[4 + wave] = ss; }
    __syncthreads();
    if (tid == 0) {
        float S  = red[0] + red[1] + red[2] + red[3];
        float SS = red[4] + red[5] + red[6] + red[7];
        float mean = S * (1.0f / D_MODEL);
        float var  = SS * (1.0f / D_MODEL) - mean * mean;
        red[0] = mean;
        red[1] = rsqrtf(var + 1e-5f);
    }
    __syncthreads();
    float mean = red[0], rstd = red[1];
    float4 gv = ((const float4*)gamma)[tid];
    float4 bv = ((const float4*)beta)[tid];
    bf16x4 o;
    o[0] = (bf16_t)((v.x - mean) * rstd * gv.x + bv.x);
    o[1] = (bf16_t)((v.y - mean) * rstd * gv.y + bv.y);
    o[2] = (bf16_t)((v.z - mean) * rstd * gv.z + bv.z);
    o[3] = (bf16_t)((v.w - mean) * rstd * gv.w + bv.w);
    ((bf16x4*)h)[(size_t)row * (D_MODEL / 4) + tid] = o;
}

// ------------------------------------------ GEMM 256x256, 8-phase, persistent
// A: bf16 (M,K) row-major.  Bt: bf16 (N,K) row-major.
// PERSISTENT STREAM-K: grid = 256 (1 block/CU). Each block owns one 256-row
// m-band and TPB consecutive 256-col n-tiles, processed as ONE continuous
// stream of S = TPB*KT K-tiles through the 8-phase pipeline. At output-tile
// boundaries the prefetcher stages the NEXT tile's k=0.. data (no drain), so
// the epilogue of tile t overlaps the in-flight loads of tile t+1. This
// removes r1's per-round serialization (4 serial blocks/CU on FFN1, each
// paying exposed prologue fill + erff epilogue with nothing to hide behind).
// Mapping: xcd = L&7, i = L>>3; m-band = xcd + 8*(i>>2); ngrp = i&3.
// TN/TPB == 4 for all three GEMMs -> 8 blocks per XCD share each B n-tile
// stream (L2 reuse), A band stays XCD-local.
// 8-phase schedule per iteration (stream tiles s0=2it (buf0), s1=2it+1 (buf1)):
//   P1: rd A.m0-3+B.n0-1(buf0) | stage A(s1).h0->buf1 | mfma
//   P2: rd B.n2-3(buf0)        | stage A(s1).h1->buf1 | mfma
//   P3: rd A.m4-7(buf0)        | stage B(s2).h0->buf0 | mfma
//   P4:                        | stage B(s2).h1->buf0 | mfma | vmcnt(4)
//   P5-P8: mirror on buf1, staging A(s2)->buf0, B(s3)->buf1 | vmcnt(4) @P8
// vmcnt(4) at P4/P8 keeps the newest 2 phases' loads in flight while
// guaranteeing tile s1 (resp. s2) fully landed. Raw s_barrier only; asm
// memory clobbers on the VM waits block unsafe load hoisting. Stream tail:
// s2/s3 clamp to S-1 (junk into regions whose reads drained phases earlier);
// vmcnt(0) after the loop so no LDS-DMA outlives the workgroup.
// MODE 2: out_bf16 = gelu_tanh(acc + bias)
// MODE 3: out_f32  = xres + acc + bias
// MODE 4: fused gate/value: n<1024 -> sigmoid(acc+bias) -> out; else acc+bias2 -> out2
#define PHASE_MID() do { __builtin_amdgcn_s_barrier(); \
    asm volatile("s_waitcnt lgkmcnt(0)" ::: "memory"); \
    __builtin_amdgcn_s_setprio(1); } while (0)
#define PHASE_END() do { __builtin_amdgcn_s_setprio(0); \
    __builtin_amdgcn_s_barrier(); } while (0)
#define PHASE_END_VM() do { __builtin_amdgcn_s_setprio(0); \
    asm volatile("s_waitcnt vmcnt(4)" ::: "memory"); \
    __builtin_amdgcn_s_barrier(); } while (0)

#define LDA4(BUF, MB) do { _Pragma("unroll") for (int m_ = 0; m_ < 4; ++m_) { \
    af[m_][0] = *(const bf16x8*)((BUF) + aoff0 + ((MB)*4 + m_) * 1024); \
    af[m_][1] = *(const bf16x8*)((BUF) + aoff1 + ((MB)*4 + m_) * 1024); } } while (0)
#define LDB2(BUF, NLO) do { _Pragma("unroll") for (int n_ = 0; n_ < 2; ++n_) { \
    bfr[(NLO)+n_][0] = *(const bf16x8*)((BUF) + boff0 + ((NLO)+n_) * 1024); \
    bfr[(NLO)+n_][1] = *(const bf16x8*)((BUF) + boff1 + ((NLO)+n_) * 1024); } } while (0)
#define MFMA_HALF(MB, NLO) do { _Pragma("unroll") for (int m_ = 0; m_ < 4; ++m_) { \
    _Pragma("unroll") for (int n_ = 0; n_ < 2; ++n_) { \
        acc[(MB)*4 + m_][(NLO) + n_] = __builtin_amdgcn_mfma_f32_16x16x32_bf16( \
            bfr[(NLO)+n_][0], af[m_][0], acc[(MB)*4 + m_][(NLO) + n_], 0, 0, 0); \
        acc[(MB)*4 + m_][(NLO) + n_] = __builtin_amdgcn_mfma_f32_16x16x32_bf16( \
            bfr[(NLO)+n_][1], af[m_][1], acc[(MB)*4 + m_][(NLO) + n_], 0, 0, 0); } } } while (0)

template <int MODE, int TN, int TPB, int LKT>
__global__ __launch_bounds__(512, 2)
void gemm256(const bf16_t* __restrict__ A, const bf16_t* __restrict__ Bt,
             const float* __restrict__ bias, const float* __restrict__ bias2,
             const float* __restrict__ xres,
             void* __restrict__ out, void* __restrict__ out2,
             int M, int N, int K) {
    __shared__ __align__(16) bf16_t lds[2][2][256 * 64];   // [buf][A=0/B=1], 128 KiB

    const int KT = 1 << LKT;       // K-tiles per output tile (K/64)
    const int S  = TPB * KT;       // stream length
    const int NI = S >> 1;         // iterations (2 K-tiles each)

    const int tid  = threadIdx.x;
    const int lane = tid & 63;
    const int wave = tid >> 6;
    const int wm   = wave >> 2;      // 0..1  (m half)
    const int wn   = wave & 3;       // 0..3  (n quarter)

    const int L    = blockIdx.x;
    const int i    = L >> 3;
    const int ngrp = i & 3;                       // TN/TPB == 4 for all shapes
    const int mb   = (L & 7) + 8 * (i >> 2);      // XCD-local m-band
    const int m0   = mb * 256;
    const int n00  = ngrp * TPB * 256;            // first owned n-tile

    f32x4 acc[8][4];
    #pragma unroll
    for (int ii = 0; ii < 8; ii++)
        #pragma unroll
        for (int j = 0; j < 4; j++) acc[ii][j] = (f32x4){0.f, 0.f, 0.f, 0.f};

    // staging invariants: row = tid>>3 (0..63 per half-load), source col8
    // pre-swizzled by row&7 so linear LDS holds the XOR layout.
    const int rr = tid >> 3;                        // 0..63
    const int sc = ((tid & 7) ^ (rr & 7)) * 8;      // swizzled col (bf16 units)
    const bf16_t* pa0 = A  + ((size_t)(m0  + rr)) * K + sc;
    const bf16_t* pb0 = Bt + ((size_t)(n00 + rr)) * K + sc;
    const size_t rstep   = (size_t)64 * K;          // rows 64..127 of a half
    const size_t hstep   = rstep * 2;               // half-tile stride (128 rows)
    const size_t nstride = (size_t)256 * K;         // next n-tile of B

    // stream-tile address helpers (A is periodic in KT: same m-band every tile)
    #define PA(s) (pa0 + (((s) & (KT - 1)) << 6))
    #define PB(s) (pb0 + (size_t)((s) >> LKT) * nstride + (((s) & (KT - 1)) << 6))

    // frag-read invariants
    const int l16 = lane & 15, quad = lane >> 4, swz = l16 & 7;
    const int aoff0 = (wm*128 + l16)*64 + ((quad    ) ^ swz)*8;
    const int aoff1 = (wm*128 + l16)*64 + ((quad + 4) ^ swz)*8;
    const int boff0 = (wn*64  + l16)*64 + ((quad    ) ^ swz)*8;
    const int boff1 = (wn*64  + l16)*64 + ((quad + 4) ^ swz)*8;

    bf16_t* LA0 = &lds[0][0][0]; bf16_t* LB0 = &lds[0][1][0];
    bf16_t* LA1 = &lds[1][0][0]; bf16_t* LB1 = &lds[1][1][0];

    auto STAGE = [&](const bf16_t* gsrc, bf16_t* dst) {
        load_lds_128(gsrc,         dst + tid * 8);
        load_lds_128(gsrc + rstep, dst + 4096 + tid * 8);
    };

    // prologue: B(0), A(0), B(1)  (6 half-tiles = 12 loads/wave-slice)
    STAGE(PB(0),         LB0);
    STAGE(PB(0) + hstep, LB0 + 8192);
    STAGE(PA(0),         LA0);
    STAGE(PA(0) + hstep, LA0 + 8192);
    STAGE(PB(1),         LB1);
    STAGE(PB(1) + hstep, LB1 + 8192);
    asm volatile("s_waitcnt vmcnt(4)" ::: "memory");   // tile 0 landed
    __builtin_amdgcn_s_barrier();

    #pragma unroll 1
    for (int it = 0; it < NI; ++it) {
        const int s1 = 2*it + 1;
        const int s2 = (2*it + 2 < S) ? 2*it + 2 : S - 1;   // clamp = tail junk
        const int s3 = (2*it + 3 < S) ? 2*it + 3 : S - 1;
        const bf16_t* a1 = PA(s1);
        const bf16_t* a2 = PA(s2);
        const bf16_t* b2 = PB(s2);
        const bf16_t* b3 = PB(s3);

        bf16x8 af[4][2], bfr[4][2];

        // P1
        LDA4(LA0, 0); LDB2(LB0, 0);
        STAGE(a1, LA1);
        PHASE_MID(); MFMA_HALF(0, 0); PHASE_END();
        // P2
        LDB2(LB0, 2);
        STAGE(a1 + hstep, LA1 + 8192);
        PHASE_MID(); MFMA_HALF(0, 2); PHASE_END();
        // P3
        LDA4(LA0, 1);
        STAGE(b2, LB0);
        PHASE_MID(); MFMA_HALF(1, 0); PHASE_END();
        // P4
        STAGE(b2 + hstep, LB0 + 8192);
        PHASE_MID(); MFMA_HALF(1, 2); PHASE_END_VM();   // tile s1 landed
        // P5
        LDA4(LA1, 0); LDB2(LB1, 0);
        STAGE(a2, LA0);
        PHASE_MID(); MFMA_HALF(0, 0); PHASE_END();
        // P6
        LDB2(LB1, 2);
        STAGE(a2 + hstep, LA0 + 8192);
        PHASE_MID(); MFMA_HALF(0, 2); PHASE_END();
        // P7
        LDA4(LA1, 1);
        STAGE(b3, LB1);
        PHASE_MID(); MFMA_HALF(1, 0); PHASE_END();
        // P8
        STAGE(b3 + hstep, LB1 + 8192);
        PHASE_MID(); MFMA_HALF(1, 2); PHASE_END_VM();   // tile s2 landed

        // ---- output-tile boundary: epilogue overlaps next tile's in-flight
        // loads (staged at P5-P8 above). Stores inflate vmcnt; the next
        // vmcnt(4) simply over-waits on them (correct, stores are older
        // than the protected loads).
        if (((it + 1) & ((KT >> 1) - 1)) == 0) {
            const int tdone = (2*it + 1) >> LKT;
            const int nn0 = n00 + tdone * 256;
            #pragma unroll
            for (int mt = 0; mt < 8; ++mt) {
                int row = m0 + wm * 128 + mt * 16 + l16;
                #pragma unroll
                for (int nt = 0; nt < 4; ++nt) {
                    int col = nn0 + wn * 64 + nt * 16 + quad * 4;
                    f32x4 a = acc[mt][nt];
                    if (MODE == 4) {
                        bool isV = (nn0 >= 1024);         // tile-uniform
                        int c1 = col & 1023;
                        float4 bv = *(const float4*)((isV ? bias2 : bias) + c1);
                        float4 val;
                        val.x = a[0] + bv.x; val.y = a[1] + bv.y;
                        val.z = a[2] + bv.z; val.w = a[3] + bv.w;
                        if (!isV) {
                            val.x = 1.0f / (1.0f + __expf(-val.x));
                            val.y = 1.0f / (1.0f + __expf(-val.y));
                            val.z = 1.0f / (1.0f + __expf(-val.z));
                            val.w = 1.0f / (1.0f + __expf(-val.w));
                        }
                        bf16x4 p;
                        p[0] = (bf16_t)val.x; p[1] = (bf16_t)val.y;
                        p[2] = (bf16_t)val.z; p[3] = (bf16_t)val.w;
                        bf16_t* o = (bf16_t*)(isV ? out2 : out);
                        *(bf16x4*)(o + (size_t)row * 1024 + c1) = p;
                    } else if (MODE == 2) {
                        float4 bv = *(const float4*)(bias + col);
                        bf16x4 p;
                        p[0] = (bf16_t)gelu_f(a[0] + bv.x);
                        p[1] = (bf16_t)gelu_f(a[1] + bv.y);
                        p[2] = (bf16_t)gelu_f(a[2] + bv.z);
                        p[3] = (bf16_t)gelu_f(a[3] + bv.w);
                        *(bf16x4*)((bf16_t*)out + (size_t)row * N + col) = p;
                    } else { // MODE 3
                        float4 bv = *(const float4*)(bias + col);
                        float4 xr = *(const float4*)(xres + (size_t)row * N + col);
                        float4 val;
                        val.x = xr.x + a[0] + bv.x; val.y = xr.y + a[1] + bv.y;
                        val.z = xr.z + a[2] + bv.z; val.w = xr.w + a[3] + bv.w;
                        *(float4*)((float*)out + (size_t)row * N + col) = val;
                    }
                    acc[mt][nt] = (f32x4){0.f, 0.f, 0.f, 0.f};
                }
            }
        }
    }

    // drain tail junk LDS-DMA before the workgroup can retire
    asm volatile("s_waitcnt vmcnt(0)" ::: "memory");
    #undef PA
    #undef PB
}

// ---------------------------------------------------------------- scan
// phase A: per-chunk sums of g and g*v
__global__ __launch_bounds__(256)
void scan_partial(const bf16_t* __restrict__ g, const bf16_t* __restrict__ v,
                  float* __restrict__ sg, float* __restrict__ sgv) {
    int dt = blockIdx.x & 1;
    int c  = (blockIdx.x >> 1) & (NCHUNK - 1);
    int b  = blockIdx.x >> 7;
    int d  = dt * 512 + threadIdx.x * 2;
    float s0 = 0.f, s1 = 0.f, t0 = 0.f, t1 = 0.f;
    for (int i = 0; i < LCHUNK; i++) {
        int s = c * LCHUNK + i;
        size_t idx = ((size_t)(b * SEQ + s)) * D_MODEL + d;
        float2 gf = bf16pair_to_f2(*(const unsigned int*)(g + idx));
        float2 vf = bf16pair_to_f2(*(const unsigned int*)(v + idx));
        s0 += gf.x; s1 += gf.y;
        t0 += gf.x * vf.x; t1 += gf.y * vf.y;
    }
    size_t o = ((size_t)(b * NCHUNK + c)) * D_MODEL + d;
    sg[o] = s0;  sg[o + 1] = s1;
    sgv[o] = t0; sgv[o + 1] = t1;
}

// phase B+C fused: each block sums partials of chunks < c (2 MB, L2-resident),
// then applies x_new = x + cumsum(g*v)/(cumsum(g)+eps)
__global__ __launch_bounds__(256)
void scan_apply(const bf16_t* __restrict__ g, const bf16_t* __restrict__ v,
                const float* __restrict__ x, const float* __restrict__ sg,
                const float* __restrict__ sgv, float* __restrict__ out) {
    int dt = blockIdx.x & 1;
    int c  = (blockIdx.x >> 1) & (NCHUNK - 1);
    int b  = blockIdx.x >> 7;
    int d  = dt * 512 + threadIdx.x * 2;
    float rg0 = 0.f, rg1 = 0.f, rv0 = 0.f, rv1 = 0.f;
    for (int p = 0; p < c; p++) {
        size_t o = ((size_t)(b * NCHUNK + p)) * D_MODEL + d;
        float2 a  = *(const float2*)(sg + o);
        float2 bb = *(const float2*)(sgv + o);
        rg0 += a.x;  rg1 += a.y;
        rv0 += bb.x; rv1 += bb.y;
    }
    for (int i = 0; i < LCHUNK; i++) {
        int s = c * LCHUNK + i;
        size_t idx = ((size_t)(b * SEQ + s)) * D_MODEL + d;
        float2 gf = bf16pair_to_f2(*(const unsigned int*)(g + idx));
        float2 vf = bf16pair_to_f2(*(const unsigned int*)(v + idx));
        rv0 += gf.x * vf.x; rg0 += gf.x;
        rv1 += gf.y * vf.y; rg1 += gf.y;
        float2 xv = *(const float2*)(x + idx);
        float2 ov;
        ov.x = xv.x + rv0 / (rg0 + 1e-6f);
        ov.y = xv.y + rv1 / (rg1 + 1e-6f);
        *(float2*)(out + idx) = ov;
    }
}

// ---------------------------------------------------------------- launcher
extern "C" void kernel_launch(void* const* d_in, const int* in_sizes, int n_in,
                              void* d_out, int out_size, void* d_ws, size_t ws_size,
                              hipStream_t stream) {
    (void)in_sizes; (void)n_in; (void)out_size; (void)ws_size;
    const float* x       = (const float*)d_in[0];
    const float* ln1_g   = (const float*)d_in[1];
    const float* ln1_b   = (const float*)d_in[2];
    const float* ln2_g   = (const float*)d_in[3];
    const float* ln2_b   = (const float*)d_in[4];
    const float* gate_w  = (const float*)d_in[5];
    const float* gate_b  = (const float*)d_in[6];
    const float* value_w = (const float*)d_in[7];
    const float* value_b = (const float*)d_in[8];
    const float* ffn_w1  = (const float*)d_in[9];
    const float* ffn_b1  = (const float*)d_in[10];
    const float* ffn_w2  = (const float*)d_in[11];
    const float* ffn_b2  = (const float*)d_in[12];
    float* out = (float*)d_out;

    char* ws = (char*)d_ws;
    const size_t MB = 1024 * 1024;
    bf16_t* wgv_t = (bf16_t*)(ws + 0 * MB);     // (2048,1024) bf16   4 MB
    bf16_t* w1_t  = (bf16_t*)(ws + 4 * MB);     // (4096,1024) bf16   8 MB
    bf16_t* w2_t  = (bf16_t*)(ws + 12 * MB);    // (1024,4096) bf16   8 MB
    bf16_t* h     = (bf16_t*)(ws + 20 * MB);    // (16384,1024) bf16 32 MB (reused as h2)
    bf16_t* g     = (bf16_t*)(ws + 52 * MB);    // (16384,1024) bf16 32 MB
    bf16_t* v     = (bf16_t*)(ws + 84 * MB);    // (16384,1024) bf16 32 MB
    float*  sg    = (float*)(ws + 116 * MB);    // (4,64,1024) f32    1 MB
    float*  sgv   = (float*)(ws + 117 * MB);    // (4,64,1024) f32    1 MB
    bf16_t* act   = (bf16_t*)(ws + 118 * MB);   // (16384,4096) bf16 128 MB

    // 1. all weight transposes in one launch
    transpose_all<<<10240, 256, 0, stream>>>(gate_w, value_w, ffn_w1, ffn_w2,
                                             wgv_t, w1_t, w2_t);

    // 2. h = LN1(x)
    ln_kernel<<<M_ROWS, 256, 0, stream>>>(x, ln1_g, ln1_b, h);

    // 3. fused: g = sigmoid(h@gate_w + gate_b); v = h@value_w + value_b
    //    TN=8, TPB=2, KT=16 -> 256 persistent blocks
    gemm256<4, 8, 2, 4><<<256, 512, 0, stream>>>(
        h, wgv_t, gate_b, value_b, nullptr, g, v, M_ROWS, 2048, 1024);

    // 4. x_new = x + cumsum(g*v)/(cumsum(g)+eps)  -> d_out
    scan_partial<<<BATCH * NCHUNK * 2, 256, 0, stream>>>(g, v, sg, sgv);
    scan_apply<<<BATCH * NCHUNK * 2, 256, 0, stream>>>(g, v, x, sg, sgv, out);

    // 5. h2 = LN2(x_new)
    ln_kernel<<<M_ROWS, 256, 0, stream>>>(out, ln2_g, ln2_b, h);

    // 6. act = gelu(h2@ffn_w1 + ffn_b1)   TN=16, TPB=4, KT=16
    gemm256<2, 16, 4, 4><<<256, 512, 0, stream>>>(
        h, w1_t, ffn_b1, nullptr, nullptr, act, nullptr, M_ROWS, 4096, 1024);

    // 7. out = x_new + act@ffn_w2 + ffn_b2   TN=4, TPB=1, KT=64
    gemm256<3, 4, 1, 6><<<256, 512, 0, stream>>>(
        act, w2_t, ffn_b2, nullptr, out, out, nullptr, M_ROWS, 1024, 4096);
}